// Round 1
// baseline (1745.938 us; speedup 1.0000x reference)
//
#include <hip/hip_runtime.h>

// TruncatedHistoryAttn, round 7.
// Phase 1 (unchanged): fp32 tiled GEMM  A = H@W1 (-> ws), B2 = H@W2 (-> d_out).
// Phase 2 restructured: partial-score exchange instead of c-row exchange.
//  - Each WG owns cols [g*64,g*64+64) of W3 (AGPRs, as before) and keeps the
//    5-deep ring of ITS OWN 64 columns of C = tilde@W3 in wave-0 registers.
//  - Scores: tanh(A+B2+C)*v computed locally over own cols (wave 0 only),
//    5 partial scalars published per WG per step (one 256B line/batch),
//    vs the previous full 512-float c-row round trip + 8x-redundant full-row
//    tanh/softmax in every WG.
//  - Consumers poll 8 flags, load 40 partials (one line), 3x shfl_xor combine,
//    softmax once in wave 0, broadcast 5 weights via LDS; every WG rebuilds the
//    full tilde row locally from its own tl ring.
//  - Barriers per step: 3 (weights ready / tlds ready / pm ready), was 4.
//  - All scoring is pre-poll now (rings are local); only combine+softmax is
//    post-poll. A/B2 prefetch (64B/wave) issued between flag store and poll.
// Next candidates (not this round): W3 in plain VGPRs (drop 64 accvgpr_reads
// from matvec), distributed per-wave scoring to shorten wave-0 serial section.

#define BB 32
#define SS 512
#define DD 512
#define NS 5
#define KWG 8

#define A_ELEMS    ((size_t)BB * SS * DD)          // 32 MB
#define YBUF_ELEMS ((size_t)2 * BB * DD)           // 128 KB region (part uses it)
#define FLAGS_OFF  ((A_ELEMS + YBUF_ELEMS) * 4)
#define FLAGS_BYTES ((size_t)BB * 64 * 4)          // 8 KB (256B line per batch)
#define WS_NEED    (FLAGS_OFF + FLAGS_BYTES)

typedef __attribute__((ext_vector_type(4))) float f32x4;

// ---------------- Phase 1: A = H@W1, B2 = H@W2 (fp32) ----------------
__global__ void __launch_bounds__(256) th_phase1(
    const float* __restrict__ H, const float* __restrict__ W1,
    const float* __restrict__ W2, float* __restrict__ A, float* __restrict__ B2) {
  const int tid = threadIdx.x;
  const int mt = blockIdx.x >> 3;
  const int nt = blockIdx.x & 7;
  const int m0 = mt << 6, n0 = nt << 6;
  __shared__ float Ht[64][20];
  __shared__ float Wt1[16][64];
  __shared__ float Wt2[16][64];
  const int tx = tid & 15, ty = tid >> 4;
  const int sr = tid >> 2, sk = (tid & 3) << 2;
  const int wr = tid >> 4, wn = (tid & 15) << 2;
  float a1[4][4] = {{0.f}}, a2[4][4] = {{0.f}};

  for (int k0 = 0; k0 < DD; k0 += 16) {
    float4 hv  = *(const float4*)&H[(size_t)(m0 + sr) * DD + k0 + sk];
    float4 w1v = *(const float4*)&W1[(size_t)(k0 + wr) * DD + n0 + wn];
    float4 w2v = *(const float4*)&W2[(size_t)(k0 + wr) * DD + n0 + wn];
    *(float4*)&Ht[sr][sk]  = hv;
    *(float4*)&Wt1[wr][wn] = w1v;
    *(float4*)&Wt2[wr][wn] = w2v;
    __syncthreads();
#pragma unroll
    for (int kq = 0; kq < 16; kq += 4) {
      float hs[4][4];
#pragma unroll
      for (int i = 0; i < 4; ++i) {
        float4 h4 = *(const float4*)&Ht[ty * 4 + i][kq];
        hs[i][0] = h4.x; hs[i][1] = h4.y; hs[i][2] = h4.z; hs[i][3] = h4.w;
      }
#pragma unroll
      for (int kk = 0; kk < 4; ++kk) {
        float4 w1f = *(const float4*)&Wt1[kq + kk][tx * 4];
        float4 w2f = *(const float4*)&Wt2[kq + kk][tx * 4];
#pragma unroll
        for (int i = 0; i < 4; ++i) {
          float h = hs[i][kk];
          a1[i][0] = fmaf(h, w1f.x, a1[i][0]);
          a1[i][1] = fmaf(h, w1f.y, a1[i][1]);
          a1[i][2] = fmaf(h, w1f.z, a1[i][2]);
          a1[i][3] = fmaf(h, w1f.w, a1[i][3]);
          a2[i][0] = fmaf(h, w2f.x, a2[i][0]);
          a2[i][1] = fmaf(h, w2f.y, a2[i][1]);
          a2[i][2] = fmaf(h, w2f.z, a2[i][2]);
          a2[i][3] = fmaf(h, w2f.w, a2[i][3]);
        }
      }
    }
    __syncthreads();
  }
#pragma unroll
  for (int i = 0; i < 4; ++i) {
    float4 o1 = make_float4(a1[i][0], a1[i][1], a1[i][2], a1[i][3]);
    float4 o2 = make_float4(a2[i][0], a2[i][1], a2[i][2], a2[i][3]);
    size_t off = (size_t)(m0 + ty * 4 + i) * DD + n0 + tx * 4;
    *(float4*)&A[off]  = o1;
    *(float4*)&B2[off] = o2;
  }
}

// ---------------- Phase 2: the recurrence ----------------
// grid 256 = 8 WGs/batch; bid = g*32+b -> all siblings on one XCD (mod-8 rr).
__global__ void __launch_bounds__(512) th_phase2(
    const float* __restrict__ H, const float* __restrict__ v,
    const float* __restrict__ W3, const float* __restrict__ A,
    float* __restrict__ Ob,  // d_out: holds B2, overwritten with tilde rows
    float* __restrict__ part, unsigned int* __restrict__ flags) {
  const int tid = threadIdx.x;
  const int b = blockIdx.x & 31;
  const int g = blockIdx.x >> 5;     // 0..7: cols [g*64, g*64+64)
  const int q = tid >> 6;            // wave id == k-segment 0..7 (64 k each)
  const int ln = tid & 63;
  const int col = (g << 6) + ln;

  __shared__ float tlds[DD];         // tilde_t row
  __shared__ float pm[DD];           // matvec partials [q*64 + ln]
  __shared__ float wl[8];            // softmax weights broadcast

  // ---- W3 slice into AGPRs: wa[i] = W3[q*64+i][col], i = 0..63.
  float wa[64];
#pragma unroll
  for (int i = 0; i < 64; ++i) {
    float t = W3[(size_t)(q * 64 + i) * DD + col];
    asm volatile("v_accvgpr_write_b32 %0, %1" : "=a"(wa[i]) : "v"(t));
  }

  const float* Hb = H + (size_t)b * SS * DD;
  const float* Ab = A + (size_t)b * SS * DD;
  float* Op = Ob + (size_t)b * SS * DD;
  float* pb = part + (size_t)b * 64;     // + slot*BB*64 + g*8 + j
  unsigned int* fb = flags + b * 64;     // 8 flags, own 256B line

  // wave-0 local state: own-column rings (row s lives in slot s % 5)
  float v_col = 0.f, bt_cur = 0.f, aN_cur = 0.f;
  float aA[NS] = {0.f, 0.f, 0.f, 0.f, 0.f};
  float cC[NS] = {0.f, 0.f, 0.f, 0.f, 0.f};
  if (tid < 64) {
    v_col  = v[col];
    bt_cur = Op[col];                // B2 row 0 at own col
  }
  float tl[NS] = {0.f, 0.f, 0.f, 0.f, 0.f};
  float tld_prev = 0.f;
  float h_cur = Hb[tid];

  for (int t5 = 0; t5 < 515; t5 += 5) {
#pragma unroll
    for (int p = 0; p < NS; ++p) {
      const int t = t5 + p;
      if (t < SS) {
        // ================= wave-0 serial section =================
        if (tid < 64) {
          aA[(p + 4) % NS] = aN_cur;   // A row t-1 enters slot (t-1)%5

          // ---- partial scores over own 64 cols (all 5 rows, pre-poll)
          float sj[NS];
#pragma unroll
          for (int j = 0; j < NS; ++j) {
            float x = aA[(p + j) % NS] + bt_cur + cC[(p + j) % NS];
            float e = __expf(2.0f * x);
            sj[j] = (1.0f - 2.0f / (e + 1.0f)) * v_col;
          }
#pragma unroll
          for (int j = 0; j < NS; ++j) {
#pragma unroll
            for (int off = 32; off >= 1; off >>= 1)
              sj[j] += __shfl_xor(sj[j], off, 64);
          }
          // lane j (j<5) stores total j: one predicated store, one 256B line
          float onev = sj[0];
          onev = (ln == 1) ? sj[1] : onev;
          onev = (ln == 2) ? sj[2] : onev;
          onev = (ln == 3) ? sj[3] : onev;
          onev = (ln == 4) ? sj[4] : onev;
          float* ps = pb + (size_t)(t & 1) * BB * 64;
          if (ln < NS)
            __hip_atomic_store(&ps[(g << 3) + ln], onev,
                               __ATOMIC_RELAXED, __HIP_MEMORY_SCOPE_AGENT);
          asm volatile("s_waitcnt vmcnt(0)" ::: "memory");
          if (ln == 0)
            __hip_atomic_store(&fb[g], (unsigned)(t + 1),
                               __ATOMIC_RELAXED, __HIP_MEMORY_SCOPE_AGENT);

          // ---- prefetch next-step operands (hidden under the poll)
          float aN_nxt = 0.f, bt_nxt = 0.f;
          if (t + 1 < SS) {
            aN_nxt = Ab[(size_t)t * DD + col];        // A row t, used at t+1
            bt_nxt = Op[(size_t)(t + 1) * DD + col];  // B2 row t+1
          }

          // ---- poll siblings
          if (ln < KWG) {
            while (__hip_atomic_load(&fb[ln], __ATOMIC_RELAXED,
                                     __HIP_MEMORY_SCOPE_AGENT) < (unsigned)(t + 1)) { }
          }

          // ---- combine 8x5 partials (one line), softmax once
          float pv = __hip_atomic_load(&ps[ln], __ATOMIC_RELAXED,
                                       __HIP_MEMORY_SCOPE_AGENT);
          pv += __shfl_xor(pv, 8, 64);
          pv += __shfl_xor(pv, 16, 64);
          pv += __shfl_xor(pv, 32, 64);   // lane l: total for j = l&7
          float sc0 = __shfl(pv, 0, 64);
          float sc1 = __shfl(pv, 1, 64);
          float sc2 = __shfl(pv, 2, 64);
          float sc3 = __shfl(pv, 3, 64);
          float sc4 = __shfl(pv, 4, 64);
          float mx = fmaxf(fmaxf(fmaxf(sc0, sc1), fmaxf(sc2, sc3)), sc4);
          float e0 = __expf(sc0 - mx), e1 = __expf(sc1 - mx);
          float e2 = __expf(sc2 - mx), e3 = __expf(sc3 - mx);
          float e4 = __expf(sc4 - mx);
          float inv = 1.0f / (e0 + e1 + e2 + e3 + e4);
          if (ln == 0) {
            wl[0] = e0 * inv; wl[1] = e1 * inv; wl[2] = e2 * inv;
            wl[3] = e3 * inv; wl[4] = e4 * inv;
          }
          bt_cur = bt_nxt; aN_cur = aN_nxt;
        }
        __syncthreads();                                     // A: weights ready

        // ================= all threads: tilde row =================
        float h_nxt = 0.f;
        if (t + 1 < SS) h_nxt = Hb[(size_t)(t + 1) * DD + tid];
        float w0 = wl[0], w1 = wl[1], w2 = wl[2], w3 = wl[3], w4 = wl[4];
        float hh = w0 * tl[p];
        hh = fmaf(w1, tl[(p + 1) % NS], hh);
        hh = fmaf(w2, tl[(p + 2) % NS], hh);
        hh = fmaf(w3, tl[(p + 3) % NS], hh);
        hh = fmaf(w4, tl[(p + 4) % NS], hh);
        float tld = h_cur + fmaxf(hh, 0.f);
        tl[p] = tld;                  // row t enters slot t%5
        tlds[tid] = tld;
        // all siblings consumed B2 row t (flags >= t+1) -> row t-1 dead
        if (g == 0 && t >= 1) Op[(size_t)(t - 1) * DD + tid] = tld_prev;
        __syncthreads();                                     // B: tlds ready

        // ================= matvec: own 64 cols, k in [q*64, q*64+64)
        float q0 = 0.f, q1 = 0.f, q2 = 0.f, q3 = 0.f;
        const f32x4* tv = (const f32x4*)&tlds[q << 6];
#pragma unroll
        for (int i = 0; i < 16; ++i) {
          f32x4 t4 = tv[i];
          float x0, x1, x2, x3;
          asm volatile("v_accvgpr_read_b32 %0, %1" : "=v"(x0) : "a"(wa[4 * i + 0]));
          asm volatile("v_accvgpr_read_b32 %0, %1" : "=v"(x1) : "a"(wa[4 * i + 1]));
          asm volatile("v_accvgpr_read_b32 %0, %1" : "=v"(x2) : "a"(wa[4 * i + 2]));
          asm volatile("v_accvgpr_read_b32 %0, %1" : "=v"(x3) : "a"(wa[4 * i + 3]));
          q0 = fmaf(t4.x, x0, q0);
          q1 = fmaf(t4.y, x1, q1);
          q2 = fmaf(t4.z, x2, q2);
          q3 = fmaf(t4.w, x3, q3);
        }
        pm[tid] = (q0 + q1) + (q2 + q3);
        __syncthreads();                                     // C: pm ready

        // wave 0: cross-segment reduce -> c row t into own ring (no publish)
        if (tid < 64) {
          float cs = 0.f;
#pragma unroll
          for (int s = 0; s < 8; ++s) cs += pm[s * 64 + ln];
          cC[p] = cs;                 // row t in slot t%5
        }
        tld_prev = tld;
        h_cur = h_nxt;
      }
    }
  }
  if (g == 0) Op[(size_t)(SS - 1) * DD + tid] = tld_prev;
}

extern "C" void kernel_launch(void* const* d_in, const int* in_sizes, int n_in,
                              void* d_out, int out_size, void* d_ws, size_t ws_size,
                              hipStream_t stream) {
  const float* H  = (const float*)d_in[0];
  const float* v  = (const float*)d_in[1];
  const float* W1 = (const float*)d_in[2];
  const float* W2 = (const float*)d_in[3];
  const float* W3 = (const float*)d_in[4];
  float* out = (float*)d_out;

  if (ws_size < WS_NEED) return;

  float* A    = (float*)d_ws;
  float* part = A + A_ELEMS;
  unsigned int* flags = (unsigned int*)((char*)d_ws + FLAGS_OFF);

  (void)hipMemsetAsync(flags, 0, FLAGS_BYTES, stream);
  hipLaunchKernelGGL(th_phase1, dim3(256 * 8), dim3(256), 0, stream,
                     H, W1, W2, A, out);
  hipLaunchKernelGGL(th_phase2, dim3(BB * KWG), dim3(512), 0, stream,
                     H, v, W3, A, out, part, flags);
}